// Round 1
// baseline (140.426 us; speedup 1.0000x reference)
//
#include <hip/hip_runtime.h>

// Problem: B=8, C=256, H=W=128.
// y1 = m1[c] ? x0 : x1 ; y2 = m2[c] ? x1 : x0
// m = (|w| >= threshold) where threshold comes from a 256-bin histogram
// "first valley" search (torch.histc port).

#define NCH 256
#define HW4 4096   // (128*128)/4 float4 per channel plane

// One block, 256 threads. Computes both channel masks, packs into code[c]:
// bit0 = m1[c], bit1 = m2[c].
__global__ __launch_bounds__(256) void mask_kernel(
    const float* __restrict__ w1,
    const float* __restrict__ w2,
    unsigned int* __restrict__ code)
{
    const int t = threadIdx.x;            // 0..255, one per channel
    __shared__ float red[NCH];
    __shared__ int   hist[NCH];

    unsigned int mycode = 0;

    for (int pass = 0; pass < 2; ++pass) {
        const float* w = (pass == 0) ? w1 : w2;
        const float b = fabsf(w[t]);

        // ---- min reduce ----
        red[t] = b; __syncthreads();
        for (int s = 128; s > 0; s >>= 1) {
            if (t < s) red[t] = fminf(red[t], red[t + s]);
            __syncthreads();
        }
        const float wmin = red[0];
        __syncthreads();

        // ---- max reduce ----
        red[t] = b; __syncthreads();
        for (int s = 128; s > 0; s >>= 1) {
            if (t < s) red[t] = fmaxf(red[t], red[t + s]);
            __syncthreads();
        }
        const float wmax = red[0];
        __syncthreads();

        // ---- histogram (torch.histc semantics, replicated in f32 op order) ----
        hist[t] = 0; __syncthreads();
        int idx = (int)floorf((b - wmin) / (wmax - wmin) * 256.0f);
        idx = idx < 0 ? 0 : (idx > 255 ? 255 : idx);
        atomicAdd(&hist[idx], 1);
        __syncthreads();

        // ---- first index i with d[i] <= 0 < d[i+1], d = diff(hist) ----
        int best = 0x7fffffff;
        if (t < 254) {
            const int d0 = hist[t + 1] - hist[t];
            const int d1 = hist[t + 2] - hist[t + 1];
            if (d0 <= 0 && d1 > 0) best = t;
        }
        __syncthreads();            // everyone done reading hist
        hist[t] = best; __syncthreads();
        for (int s = 128; s > 0; s >>= 1) {
            if (t < s) hist[t] = min(hist[t], hist[t + s]);
            __syncthreads();
        }
        const int i = (hist[0] == 0x7fffffff) ? 0 : hist[0];

        // threshold = wmin + (i+2) * (wmax - wmin) / 256   (f32, ref op order)
        const float thr = wmin + (float)(i + 2) * (wmax - wmin) / 256.0f;

        if (b >= thr) mycode |= (1u << pass);
        __syncthreads();
    }

    code[t] = mycode;
}

// Grid-stride elementwise select, float4-vectorized.
__global__ __launch_bounds__(256) void select_kernel(
    const float4* __restrict__ x0,
    const float4* __restrict__ x1,
    const unsigned int* __restrict__ code,
    float4* __restrict__ y1,
    float4* __restrict__ y2,
    long long n4)
{
    const long long stride = (long long)gridDim.x * blockDim.x;
    for (long long i = (long long)blockIdx.x * blockDim.x + threadIdx.x;
         i < n4; i += stride) {
        const int c = (int)((i >> 12) & (NCH - 1));   // HW4 = 2^12 float4/plane
        const unsigned int m = code[c];
        const float4 a = x0[i];
        const float4 b = x1[i];
        y1[i] = (m & 1u) ? a : b;
        y2[i] = (m & 2u) ? b : a;
    }
}

extern "C" void kernel_launch(void* const* d_in, const int* in_sizes, int n_in,
                              void* d_out, int out_size, void* d_ws, size_t ws_size,
                              hipStream_t stream)
{
    const float* x0 = (const float*)d_in[0];
    const float* x1 = (const float*)d_in[1];
    const float* w1 = (const float*)d_in[2];
    const float* w2 = (const float*)d_in[3];

    unsigned int* code = (unsigned int*)d_ws;   // 256 codes, 1 KiB

    const long long n  = (long long)in_sizes[0];     // 8*256*128*128 = 33,554,432
    const long long n4 = n / 4;                      // 8,388,608 float4

    mask_kernel<<<1, 256, 0, stream>>>(w1, w2, code);

    float4* y1 = (float4*)d_out;
    float4* y2 = y1 + n4;

    const int block = 256;
    const int grid  = 2048;   // 256 CU * 8 blocks; grid-stride covers the rest
    select_kernel<<<grid, block, 0, stream>>>(
        (const float4*)x0, (const float4*)x1, code, y1, y2, n4);
}

// Round 2
// 100.554 us; speedup vs baseline: 1.3965x; 1.3965x over previous
//
#include <hip/hip_runtime.h>

// B=8, C=256, H=W=128 (fixed). n = 33,554,432 f32 per tensor; n4 = 2^23 float4.
// Plane = 128*128/4 = 4096 = 2^12 float4. 2048 blocks x 256 threads:
// each block covers 256 consecutive float4 per step -> channel is BLOCK-uniform.
// Two phases per thread, phase stride 2^20 float4 -> channel loop-invariant,
// so the mask branch hoists out and each path is a clean unrolled stream.
//
// y1 = m1[c] ? x0 : x1 ; y2 = m2[c] ? x1 : x0 ; code = m1 | (m2<<1)
// code==1 -> y1=y2=x0 (skip x1 read); code==2 -> y1=y2=x1 (skip x0 read).

typedef float f32x4 __attribute__((ext_vector_type(4)));

#define NCH 256

__device__ __forceinline__ void stream8(
    int base, unsigned int m, long long n4,
    const f32x4* __restrict__ x0, const f32x4* __restrict__ x1,
    f32x4* __restrict__ y1, f32x4* __restrict__ y2)
{
    if (m == 1u) {            // y1 = x0, y2 = x0  (x1 never read)
#pragma unroll
        for (int u = 0; u < 8; ++u) {
            long long i = (long long)base + ((long long)u << 20);
            if (i < n4) {
                f32x4 a = __builtin_nontemporal_load(&x0[i]);
                __builtin_nontemporal_store(a, &y1[i]);
                __builtin_nontemporal_store(a, &y2[i]);
            }
        }
    } else if (m == 2u) {     // y1 = x1, y2 = x1  (x0 never read)
#pragma unroll
        for (int u = 0; u < 8; ++u) {
            long long i = (long long)base + ((long long)u << 20);
            if (i < n4) {
                f32x4 b = __builtin_nontemporal_load(&x1[i]);
                __builtin_nontemporal_store(b, &y1[i]);
                __builtin_nontemporal_store(b, &y2[i]);
            }
        }
    } else if (m == 3u) {     // y1 = x0, y2 = x1
#pragma unroll
        for (int u = 0; u < 8; ++u) {
            long long i = (long long)base + ((long long)u << 20);
            if (i < n4) {
                f32x4 a = __builtin_nontemporal_load(&x0[i]);
                f32x4 b = __builtin_nontemporal_load(&x1[i]);
                __builtin_nontemporal_store(a, &y1[i]);
                __builtin_nontemporal_store(b, &y2[i]);
            }
        }
    } else {                  // m==0: y1 = x1, y2 = x0
#pragma unroll
        for (int u = 0; u < 8; ++u) {
            long long i = (long long)base + ((long long)u << 20);
            if (i < n4) {
                f32x4 a = __builtin_nontemporal_load(&x0[i]);
                f32x4 b = __builtin_nontemporal_load(&x1[i]);
                __builtin_nontemporal_store(b, &y1[i]);
                __builtin_nontemporal_store(a, &y2[i]);
            }
        }
    }
}

__global__ __launch_bounds__(256) void fused_kernel(
    const float* __restrict__ w1, const float* __restrict__ w2,
    const f32x4* __restrict__ x0, const f32x4* __restrict__ x1,
    f32x4* __restrict__ y1, f32x4* __restrict__ y2, long long n4)
{
    __shared__ float redf[8];
    __shared__ int   hist[NCH];
    __shared__ int   redi[4];
    __shared__ unsigned int code_s[NCH];

    const int t = threadIdx.x;          // 0..255, one channel each
    const int lane = t & 63;
    const int wid  = t >> 6;

    // ---- per-block mask recompute (cheap, overlapped across blocks) ----
    unsigned int mycode = 0;
    for (int pass = 0; pass < 2; ++pass) {
        const float* __restrict__ w = pass ? w2 : w1;
        const float b = fabsf(w[t]);

        // fused min+max wave reduction, then 4 partials via LDS
        float vmin = b, vmax = b;
#pragma unroll
        for (int off = 32; off > 0; off >>= 1) {
            vmin = fminf(vmin, __shfl_xor(vmin, off));
            vmax = fmaxf(vmax, __shfl_xor(vmax, off));
        }
        if (lane == 0) { redf[wid] = vmin; redf[4 + wid] = vmax; }
        hist[t] = 0;
        __syncthreads();
        const float wmin = fminf(fminf(redf[0], redf[1]), fminf(redf[2], redf[3]));
        const float wmax = fmaxf(fmaxf(redf[4], redf[5]), fmaxf(redf[6], redf[7]));

        // torch.histc semantics, f32 op order identical to reference
        int idx = (int)floorf((b - wmin) / (wmax - wmin) * 256.0f);
        idx = idx < 0 ? 0 : (idx > 255 ? 255 : idx);
        atomicAdd(&hist[idx], 1);
        __syncthreads();

        // first i with diff[i] <= 0 < diff[i+1]; fallback 0
        int best = 0x7fffffff;
        if (t < 254) {
            const int d0 = hist[t + 1] - hist[t];
            const int d1 = hist[t + 2] - hist[t + 1];
            if (d0 <= 0 && d1 > 0) best = t;
        }
#pragma unroll
        for (int off = 32; off > 0; off >>= 1)
            best = min(best, __shfl_xor(best, off));
        if (lane == 0) redi[wid] = best;
        __syncthreads();
        int ival = min(min(redi[0], redi[1]), min(redi[2], redi[3]));
        if (ival == 0x7fffffff) ival = 0;

        const float thr = wmin + (float)(ival + 2) * (wmax - wmin) / 256.0f;
        if (b >= thr) mycode |= (1u << pass);
        __syncthreads();   // safe reuse of hist/redf/redi next pass
    }
    code_s[t] = mycode;
    __syncthreads();

    // ---- streaming: channel is block-uniform per phase ----
    const int c0 = blockIdx.x >> 4;              // 16 blocks per plane, c0 in [0,128)
    const unsigned int m0 = code_s[c0];
    const unsigned int m1 = code_s[c0 + 128];
    const int base = blockIdx.x * 256 + t;       // < 2^19

    stream8(base,             m0, n4, x0, x1, y1, y2);
    stream8(base + (1 << 19), m1, n4, x0, x1, y1, y2);
}

extern "C" void kernel_launch(void* const* d_in, const int* in_sizes, int n_in,
                              void* d_out, int out_size, void* d_ws, size_t ws_size,
                              hipStream_t stream)
{
    const float* x0 = (const float*)d_in[0];
    const float* x1 = (const float*)d_in[1];
    const float* w1 = (const float*)d_in[2];
    const float* w2 = (const float*)d_in[3];

    const long long n  = (long long)in_sizes[0];   // 33,554,432
    const long long n4 = n / 4;                    // 8,388,608 = 2^23

    f32x4* y1 = (f32x4*)d_out;
    f32x4* y2 = y1 + n4;

    fused_kernel<<<2048, 256, 0, stream>>>(
        w1, w2, (const f32x4*)x0, (const f32x4*)x1, y1, y2, n4);
}